// Round 1
// 2451.548 us; speedup vs baseline: 1.2820x; 1.2820x over previous
//
#include <hip/hip_runtime.h>
#include <hip/hip_bf16.h>

typedef __bf16 bf16_t;
typedef __bf16 bf16x8 __attribute__((ext_vector_type(8)));
typedef __bf16 bf16x4 __attribute__((ext_vector_type(4)));
typedef float  f32x4  __attribute__((ext_vector_type(4)));

#define NTOK   4096   // B*T
#define DMODEL 1024
#define NHEAD  16
#define HDIM   64
#define TSEQ   1024
#define FDIM   4096
#define NLAYER 6
#define OUTDIM 2048

__device__ __forceinline__ float gelu_f(float x) {
    const float c = 0.7978845608028654f;  // sqrt(2/pi)
    float u = c * (x + 0.044715f * x * x * x);
    return 0.5f * x * (1.0f + tanhf(u));
}

__device__ __forceinline__ void load_lds16(const void* g, void* l) {
    __builtin_amdgcn_global_load_lds(
        (const __attribute__((address_space(1))) void*)g,
        (__attribute__((address_space(3))) void*)l, 16, 0, 0);
}

// ---------------------------------------------------------------------------
// GEMM body: C[M,N] = A[M,K](bf16) @ B[N,K](fp32)^T + bias(fp32)
// optional GELU, optional fp32 residual; out bf16 or fp32.
// ATOMIC variant: computes partial over K range [kBase, kBase+kLen) and
// atomicAdds fp32 partials into Cout (residual must pre-exist in Cout;
// bias added only when addBias). Used for split-K residual GEMMs.
// 128x128 tile, BK=32, 256 thr. A: m97 bf16 staging. B: fp32 staged via
// global_load_lds into XOR-swizzled (16B-chunk, p = c ^ (row&7)) LDS tile;
// converted to bf16 at fragment load. Swizzle keeps ds_read_b128 at 2-way.
// ---------------------------------------------------------------------------
template<bool GELU, bool RES, bool OUTBF, bool ATOMIC>
__device__ __forceinline__
void gemm_body(const bf16_t* __restrict__ A, const float* __restrict__ B,
               const float* __restrict__ bias, const float* Res,
               void* Cout, int M, int N, int K, int kBase, int kLen,
               bool addBias)
{
    __shared__ bf16_t As[128 * 32];   // 8 KB, row-major [row][32]
    __shared__ float  Bs[128 * 32];   // 16 KB, swizzled 16B chunks
    const int t = threadIdx.x;
    const int w = t >> 6, l = t & 63;
    const int wm = (w >> 1) * 64, wn = (w & 1) * 64;
    const int g = l >> 4, fr = l & 15, e = fr & 7;

    // A staging: round rd in {0,1}: row = rd*64 + (t>>2), col = (t&3)*8 bf16
    const long aRow = (long)blockIdx.x * 128 + (t >> 2);
    const int  aCol = (t & 3) * 8;
    // B staging: round rd in {0..3}: row = rd*32 + (t>>3); physical chunk = t&7;
    // logical chunk c = (t&7) ^ (row&7) -> fp32 col 4c  (row&7 == (t>>3)&7)
    const long bRow0 = (long)blockIdx.y * 128 + (t >> 3);
    const int  bCol  = (((t & 7) ^ ((t >> 3) & 7)) << 2);

    char* aBase = (char*)As + w * 1024;
    char* bBase = (char*)Bs + w * 1024;

    f32x4 acc[4][4] = {};

    for (int k0 = kBase; k0 < kBase + kLen; k0 += 32) {
        __syncthreads();
        load_lds16(A + aRow * K + (k0 + aCol),        aBase);
        load_lds16(A + (aRow + 64) * K + (k0 + aCol), aBase + 4096);
        #pragma unroll
        for (int rd = 0; rd < 4; ++rd)
            load_lds16(B + (bRow0 + rd * 32) * (long)K + (k0 + bCol),
                       bBase + rd * 4096);
        __syncthreads();

        bf16x8 af[4], bfr[4];
        #pragma unroll
        for (int mi = 0; mi < 4; ++mi)
            af[mi] = *(const bf16x8*)&As[(wm + mi * 16 + fr) * 32 + g * 8];
        #pragma unroll
        for (int ni = 0; ni < 4; ++ni) {
            const char* rp = (const char*)Bs + (wn + ni * 16 + fr) * 128;
            f32x4 lo = *(const f32x4*)(rp + ((( 2 * g )     ^ e) << 4));
            f32x4 hi = *(const f32x4*)(rp + (((2 * g + 1)   ^ e) << 4));
            bf16x8 bb;
            #pragma unroll
            for (int j = 0; j < 4; ++j) { bb[j] = (bf16_t)lo[j]; bb[4 + j] = (bf16_t)hi[j]; }
            bfr[ni] = bb;
        }
        #pragma unroll
        for (int mi = 0; mi < 4; ++mi)
            #pragma unroll
            for (int ni = 0; ni < 4; ++ni)
                acc[mi][ni] = __builtin_amdgcn_mfma_f32_16x16x32_bf16(
                    af[mi], bfr[ni], acc[mi][ni], 0, 0, 0);
    }

    // epilogue: C/D layout col = l&15, row = (l>>4)*4 + reg
    bf16_t* Cb = (bf16_t*)Cout;
    float*  Cf = (float*)Cout;
    const int r0 = g * 4, cc = fr;
    #pragma unroll
    for (int ni = 0; ni < 4; ++ni) {
        const int gc = blockIdx.y * 128 + wn + ni * 16 + cc;
        const float bv = addBias ? bias[gc] : 0.f;
        #pragma unroll
        for (int mi = 0; mi < 4; ++mi) {
            #pragma unroll
            for (int r = 0; r < 4; ++r) {
                const long gr = (long)blockIdx.x * 128 + wm + mi * 16 + r0 + r;
                float vv = acc[mi][ni][r] + bv;
                if (ATOMIC) {
                    atomicAdd(&Cf[gr * N + gc], vv);
                } else {
                    if (GELU) vv = gelu_f(vv);
                    if (RES)  vv += Res[gr * N + gc];
                    if (OUTBF) Cb[gr * N + gc] = (bf16_t)vv;
                    else       Cf[gr * N + gc] = vv;
                }
            }
        }
    }
}

template<bool GELU, bool RES, bool OUTBF>
__global__ __launch_bounds__(256, 2)
void gemm_kernel(const bf16_t* __restrict__ A, const float* __restrict__ B,
                 const float* __restrict__ bias, const float* Res,
                 void* Cout, int M, int N, int K)
{
    gemm_body<GELU, RES, OUTBF, false>(A, B, bias, Res, Cout, M, N, K, 0, K, true);
}

// Split-K residual GEMM: grid.z = splitk; each z-block accumulates a K-chunk
// and atomicAdds fp32 partials into Cout (which already holds the residual).
// Bias added by z==0 only. Raises occupancy 1 blk/CU -> splitk blk/CU.
__global__ __launch_bounds__(256, 2)
void gemm_splitk_kernel(const bf16_t* __restrict__ A, const float* __restrict__ B,
                        const float* __restrict__ bias, float* Cout,
                        int M, int N, int K, int splitk)
{
    const int kLen = K / splitk;
    gemm_body<false, false, false, true>(A, B, bias, nullptr, Cout, M, N, K,
                                         blockIdx.z * kLen, kLen,
                                         blockIdx.z == 0);
}

// Fused Q/K/V projection: grid.z in {0,1,2} selects weight/bias/output.
// One 768-block dispatch instead of 3 serial 256-block (1 blk/CU) launches.
__global__ __launch_bounds__(256, 2)
void qkv_kernel(const bf16_t* __restrict__ A,
                const float* __restrict__ B0, const float* __restrict__ B1,
                const float* __restrict__ B2,
                const float* __restrict__ b0, const float* __restrict__ b1,
                const float* __restrict__ b2,
                bf16_t* C0, bf16_t* C1, bf16_t* C2, int M, int N, int K)
{
    const int z = blockIdx.z;
    const float* B    = (z == 0) ? B0 : (z == 1) ? B1 : B2;
    const float* bias = (z == 0) ? b0 : (z == 1) ? b1 : b2;
    bf16_t*      C    = (z == 0) ? C0 : (z == 1) ? C1 : C2;
    gemm_body<false, false, true, false>(A, B, bias, nullptr, C, M, N, K, 0, K, true);
}

// ---------------------------------------------------------------------------
// LayerNorm over D=1024: fp32 in -> bf16 out. One 256-thr block per token.
// ---------------------------------------------------------------------------
__global__ __launch_bounds__(256)
void ln_kernel(const float* __restrict__ in, const float* __restrict__ w,
               const float* __restrict__ b, bf16_t* __restrict__ out)
{
    const long row = blockIdx.x;
    const int t = threadIdx.x;
    f32x4 xv = *(const f32x4*)(in + row * DMODEL + t * 4);
    float s  = xv[0] + xv[1] + xv[2] + xv[3];
    float ss = xv[0]*xv[0] + xv[1]*xv[1] + xv[2]*xv[2] + xv[3]*xv[3];
    #pragma unroll
    for (int off = 32; off; off >>= 1) {
        s  += __shfl_xor(s, off);
        ss += __shfl_xor(ss, off);
    }
    __shared__ float sbuf[4], ssbuf[4];
    if ((t & 63) == 0) { sbuf[t >> 6] = s; ssbuf[t >> 6] = ss; }
    __syncthreads();
    s  = sbuf[0] + sbuf[1] + sbuf[2] + sbuf[3];
    ss = ssbuf[0] + ssbuf[1] + ssbuf[2] + ssbuf[3];
    const float mean = s * (1.f / DMODEL);
    const float var  = ss * (1.f / DMODEL) - mean * mean;
    const float rstd = rsqrtf(var + 1e-5f);
    f32x4 wv = *(const f32x4*)(w + t * 4);
    f32x4 bv = *(const f32x4*)(b + t * 4);
    bf16x4 o4;
    #pragma unroll
    for (int j = 0; j < 4; ++j)
        o4[j] = (bf16_t)((xv[j] - mean) * rstd * wv[j] + bv[j]);
    *(bf16x4*)(out + row * DMODEL + t * 4) = o4;
}

// ---------------------------------------------------------------------------
// Flash attention (non-causal, mask==0): block = (b,h, 64 q rows), 4 waves,
// wave w owns q rows [16w,16w+16). bf16 MFMA 16x16x32, fp32 online softmax.
// K/V tiles (64s x 64d) staged per step; V stored transposed [d][s].
// Q/K/V LDS rows XOR-swizzled in 16B chunks (p = c ^ (row&7)) -> 2-way banks.
// P round-trips through per-wave LDS (C-layout -> A-layout), m120 pattern.
// Grid MUST be B*H*(T/64) = 1024 blocks (round-2 bug: launched 256).
// ---------------------------------------------------------------------------
__global__ __launch_bounds__(256)
void attn_kernel(const bf16_t* __restrict__ q, const bf16_t* __restrict__ k,
                 const bf16_t* __restrict__ v, bf16_t* __restrict__ o)
{
    __shared__ bf16_t Qs[64 * 64], Ks[64 * 64], Vs[64 * 64];
    __shared__ bf16_t Ps[4][16 * 64];
    const int t = threadIdx.x, w = t >> 6, l = t & 63;
    const int g = l >> 4, fr = l & 15, e = fr & 7;
    const int qblk = blockIdx.x & 15, bh = blockIdx.x >> 4;   // bh in 0..63
    const int b = bh >> 4, h = bh & 15;
    const long base = (long)b * TSEQ * DMODEL + h * HDIM;

    // staging map: row = t>>2 (64 rows), 16B-chunk pair c2, c2+1
    const int sr = t >> 2, c2 = (t & 3) * 2;
    const int p0 = c2 ^ (sr & 7), p1 = (c2 + 1) ^ (sr & 7);
    const int s7 = sr & 7, scs = sr >> 3;

    {   // stage Q once
        const bf16_t* qg = q + base + (long)(qblk * 64 + sr) * DMODEL + c2 * 8;
        bf16x8 a0 = *(const bf16x8*)qg, a1 = *(const bf16x8*)(qg + 8);
        *(bf16x8*)((char*)Qs + sr * 128 + p0 * 16) = a0;
        *(bf16x8*)((char*)Qs + sr * 128 + p1 * 16) = a1;
    }
    __syncthreads();
    bf16x8 qf[2];
    {
        const char* qp = (const char*)Qs + (16 * w + fr) * 128;
        qf[0] = *(const bf16x8*)(qp + ((g       ^ e) << 4));
        qf[1] = *(const bf16x8*)(qp + (((g + 4) ^ e) << 4));
    }

    float m_[4], lsum[4] = {0.f, 0.f, 0.f, 0.f};
    #pragma unroll
    for (int r = 0; r < 4; ++r) m_[r] = -1e30f;
    f32x4 oacc[4] = {};

    for (int s0 = 0; s0 < TSEQ; s0 += 64) {
        __syncthreads();
        {   // stage K tile
            const bf16_t* kg = k + base + (long)(s0 + sr) * DMODEL + c2 * 8;
            bf16x8 a0 = *(const bf16x8*)kg, a1 = *(const bf16x8*)(kg + 8);
            *(bf16x8*)((char*)Ks + sr * 128 + p0 * 16) = a0;
            *(bf16x8*)((char*)Ks + sr * 128 + p1 * 16) = a1;
        }
        {   // stage V transposed: thread loads V[s=sr][d0..d0+16), scatters to Vs[d][s]
            const bf16_t* vg = v + base + (long)(s0 + sr) * DMODEL + (t & 3) * 16;
            bf16x8 v0 = *(const bf16x8*)vg, v1 = *(const bf16x8*)(vg + 8);
            #pragma unroll
            for (int u = 0; u < 8; ++u) {
                int d0 = (t & 3) * 16 + u;
                ((bf16_t*)((char*)Vs + d0 * 128 + ((scs ^ (d0 & 7)) << 4)))[s7] = v0[u];
                int d1 = d0 + 8;
                ((bf16_t*)((char*)Vs + d1 * 128 + ((scs ^ (d1 & 7)) << 4)))[s7] = v1[u];
            }
        }
        __syncthreads();

        // S = Q K^T  (4 s-subtiles x 2 k-steps)
        f32x4 sacc[4] = {};
        #pragma unroll
        for (int ni = 0; ni < 4; ++ni) {
            const char* kp = (const char*)Ks + (ni * 16 + fr) * 128;
            bf16x8 kf0 = *(const bf16x8*)(kp + ((g       ^ e) << 4));
            bf16x8 kf1 = *(const bf16x8*)(kp + (((g + 4) ^ e) << 4));
            sacc[ni] = __builtin_amdgcn_mfma_f32_16x16x32_bf16(qf[0], kf0, sacc[ni], 0, 0, 0);
            sacc[ni] = __builtin_amdgcn_mfma_f32_16x16x32_bf16(qf[1], kf1, sacc[ni], 0, 0, 0);
        }

        // online softmax; S row = g*4 + r (local q), col = ni*16 + fr (local s)
        #pragma unroll
        for (int r = 0; r < 4; ++r) {
            float a = fmaxf(fmaxf(sacc[0][r], sacc[1][r]),
                            fmaxf(sacc[2][r], sacc[3][r])) * 0.125f;
            #pragma unroll
            for (int off = 1; off < 16; off <<= 1) a = fmaxf(a, __shfl_xor(a, off));
            float mnew  = fmaxf(m_[r], a);
            float alpha = __expf(m_[r] - mnew);
            m_[r] = mnew;
            float sum = 0.f;
            #pragma unroll
            for (int ni = 0; ni < 4; ++ni) {
                float p = __expf(sacc[ni][r] * 0.125f - mnew);
                sum += p;
                Ps[w][(g * 4 + r) * 64 + ni * 16 + fr] = (bf16_t)p;
            }
            #pragma unroll
            for (int off = 1; off < 16; off <<= 1) sum += __shfl_xor(sum, off);
            lsum[r] = lsum[r] * alpha + sum;
            #pragma unroll
            for (int di = 0; di < 4; ++di) oacc[di][r] *= alpha;
        }

        // O += P V   (P: A-layout from per-wave LDS; V^T rows, swizzled)
        bf16x8 pf0 = *(const bf16x8*)&Ps[w][fr * 64 + g * 8];
        bf16x8 pf1 = *(const bf16x8*)&Ps[w][fr * 64 + 32 + g * 8];
        #pragma unroll
        for (int di = 0; di < 4; ++di) {
            const char* vp = (const char*)Vs + (di * 16 + fr) * 128;
            bf16x8 vf0 = *(const bf16x8*)(vp + ((g       ^ e) << 4));
            bf16x8 vf1 = *(const bf16x8*)(vp + (((g + 4) ^ e) << 4));
            oacc[di] = __builtin_amdgcn_mfma_f32_16x16x32_bf16(pf0, vf0, oacc[di], 0, 0, 0);
            oacc[di] = __builtin_amdgcn_mfma_f32_16x16x32_bf16(pf1, vf1, oacc[di], 0, 0, 0);
        }
    }

    #pragma unroll
    for (int r = 0; r < 4; ++r) {
        const float inv = 1.f / lsum[r];
        const long tq = qblk * 64 + 16 * w + g * 4 + r;
        #pragma unroll
        for (int di = 0; di < 4; ++di)
            o[base + tq * DMODEL + di * 16 + fr] = (bf16_t)(oacc[di][r] * inv);
    }
}

// ---------------------------------------------------------------------------
extern "C" void kernel_launch(void* const* d_in, const int* in_sizes, int n_in,
                              void* d_out, int out_size, void* d_ws, size_t ws_size,
                              hipStream_t stream)
{
    const float* hs    = (const float*)d_in[0];
    const float* ln1w  = (const float*)d_in[2];
    const float* ln1b  = (const float*)d_in[3];
    const float* qw    = (const float*)d_in[4];
    const float* qbias = (const float*)d_in[5];
    const float* kw    = (const float*)d_in[6];
    const float* kbias = (const float*)d_in[7];
    const float* vw    = (const float*)d_in[8];
    const float* vbias = (const float*)d_in[9];
    const float* ow    = (const float*)d_in[10];
    const float* obias = (const float*)d_in[11];
    const float* ln2w  = (const float*)d_in[12];
    const float* ln2b  = (const float*)d_in[13];
    const float* fc1w  = (const float*)d_in[14];
    const float* fc1b  = (const float*)d_in[15];
    const float* fc2w  = (const float*)d_in[16];
    const float* fc2b  = (const float*)d_in[17];
    const float* lnpw  = (const float*)d_in[18];
    const float* lnpb  = (const float*)d_in[19];
    const float* p1w   = (const float*)d_in[20];
    const float* p1b   = (const float*)d_in[21];
    const float* p2w   = (const float*)d_in[22];
    const float* p2b   = (const float*)d_in[23];

    // ws (56 MB): h fp32 16MB | x bf16 8MB | q 8 | k 8 | v 8 | +8 (fbuf tail)
    float*  h    = (float*)d_ws;
    bf16_t* x    = (bf16_t*)(h + (long)NTOK * DMODEL);
    bf16_t* qbuf = x    + (long)NTOK * DMODEL;
    bf16_t* kbuf = qbuf + (long)NTOK * DMODEL;
    bf16_t* vbuf = kbuf + (long)NTOK * DMODEL;
    bf16_t* obuf = x;      // x dead after V-proj; attention writes o here
    bf16_t* fbuf = qbuf;   // 32 MB spans q,k,v + 8MB tail

    hipMemcpyAsync(h, hs, (size_t)NTOK * DMODEL * sizeof(float),
                   hipMemcpyDeviceToDevice, stream);

    const dim3 blk(256);
    const dim3 gD(NTOK / 128, DMODEL / 128);        // N=1024, 256 blocks
    const dim3 gQKV(NTOK / 128, DMODEL / 128, 3);   // fused qkv, 768 blocks
    const dim3 gO2(NTOK / 128, DMODEL / 128, 2);    // o-proj split-K=2, 512 blocks
    const dim3 gFC2(NTOK / 128, DMODEL / 128, 4);   // fc2 split-K=4, 1024 blocks
    const dim3 gF(NTOK / 128, FDIM / 128);          // N=4096, 1024 blocks
    const dim3 gOut(NTOK / 128, OUTDIM / 128);      // N=2048, 512 blocks
    const int  gAttn = (NTOK / 64) * NHEAD;         // 1024 blocks: (b,h,qblk)

    for (int i = 0; i < NLAYER; ++i) {
        const long wD = (long)i * DMODEL * DMODEL;
        const long wF = (long)i * FDIM * DMODEL;
        ln_kernel<<<NTOK, blk, 0, stream>>>(h, ln1w + i * DMODEL, ln1b + i * DMODEL, x);
        qkv_kernel<<<gQKV, blk, 0, stream>>>(x, qw + wD, kw + wD, vw + wD,
                                             qbias + i * DMODEL, kbias + i * DMODEL, vbias + i * DMODEL,
                                             qbuf, kbuf, vbuf, NTOK, DMODEL, DMODEL);
        attn_kernel<<<gAttn, blk, 0, stream>>>(qbuf, kbuf, vbuf, obuf);
        // h += obuf @ ow^T + ob   (residual already in h)
        gemm_splitk_kernel<<<gO2, blk, 0, stream>>>(obuf, ow + wD, obias + i * DMODEL, h, NTOK, DMODEL, DMODEL, 2);
        ln_kernel<<<NTOK, blk, 0, stream>>>(h, ln2w + i * DMODEL, ln2b + i * DMODEL, x);
        gemm_kernel<true , false, true ><<<gF, blk, 0, stream>>>(x, fc1w + wF, fc1b + (long)i * FDIM, nullptr, fbuf, NTOK, FDIM, DMODEL);
        // h += fbuf @ fc2w^T + fc2b   (residual already in h)
        gemm_splitk_kernel<<<gFC2, blk, 0, stream>>>(fbuf, fc2w + wF, fc2b + i * DMODEL, h, NTOK, DMODEL, FDIM, 4);
    }

    ln_kernel<<<NTOK, blk, 0, stream>>>(h, lnpw, lnpb, x);
    gemm_kernel<true , false, true ><<<gD, blk, 0, stream>>>(x, p1w, p1b, nullptr, qbuf, NTOK, DMODEL, DMODEL);
    gemm_kernel<false, false, false><<<gOut, blk, 0, stream>>>(qbuf, p2w, p2b, nullptr, d_out, NTOK, OUTDIM, DMODEL);
}

// Round 3
// 2229.008 us; speedup vs baseline: 1.4100x; 1.0998x over previous
//
#include <hip/hip_runtime.h>
#include <hip/hip_bf16.h>

typedef __bf16 bf16_t;
typedef __bf16 bf16x8 __attribute__((ext_vector_type(8)));
typedef __bf16 bf16x4 __attribute__((ext_vector_type(4)));
typedef float  f32x4  __attribute__((ext_vector_type(4)));

#define NTOK   4096   // B*T
#define DMODEL 1024
#define NHEAD  16
#define HDIM   64
#define TSEQ   1024
#define FDIM   4096
#define NLAYER 6
#define OUTDIM 2048

__device__ __forceinline__ float gelu_f(float x) {
    const float c = 0.7978845608028654f;  // sqrt(2/pi)
    float u = c * (x + 0.044715f * x * x * x);
    return 0.5f * x * (1.0f + tanhf(u));
}

__device__ __forceinline__ void load_lds16(const void* g, void* l) {
    __builtin_amdgcn_global_load_lds(
        (const __attribute__((address_space(1))) void*)g,
        (__attribute__((address_space(3))) void*)l, 16, 0, 0);
}

// ---------------------------------------------------------------------------
// fp32 -> bf16 weight conversion (RNE, identical numerics to in-loop cast).
// 8 elems / thread, exact grid.
// ---------------------------------------------------------------------------
__global__ __launch_bounds__(256)
void cvt_kernel(const float* __restrict__ in, bf16_t* __restrict__ out)
{
    const long i = ((long)blockIdx.x * 256 + threadIdx.x) * 8;
    f32x4 a = *(const f32x4*)(in + i);
    f32x4 b = *(const f32x4*)(in + i + 4);
    bf16x8 o;
    #pragma unroll
    for (int j = 0; j < 4; ++j) { o[j] = (bf16_t)a[j]; o[4 + j] = (bf16_t)b[j]; }
    *(bf16x8*)(out + i) = o;
}

// 3-tensor variant (q/k/v weights) — one launch, grid.z selects tensor.
__global__ __launch_bounds__(256)
void cvt3_kernel(const float* __restrict__ i0, const float* __restrict__ i1,
                 const float* __restrict__ i2, bf16_t* __restrict__ o0,
                 bf16_t* __restrict__ o1, bf16_t* __restrict__ o2)
{
    const float* in  = (blockIdx.z == 0) ? i0 : (blockIdx.z == 1) ? i1 : i2;
    bf16_t*      out = (blockIdx.z == 0) ? o0 : (blockIdx.z == 1) ? o1 : o2;
    const long i = ((long)blockIdx.x * 256 + threadIdx.x) * 8;
    f32x4 a = *(const f32x4*)(in + i);
    f32x4 b = *(const f32x4*)(in + i + 4);
    bf16x8 o;
    #pragma unroll
    for (int j = 0; j < 4; ++j) { o[j] = (bf16_t)a[j]; o[4 + j] = (bf16_t)b[j]; }
    *(bf16x8*)(out + i) = o;
}

// ---------------------------------------------------------------------------
// GEMM v2: C[M,N] = A[M,K](bf16) @ B[N,K]^T + bias; B bf16 (BF16B) or fp32.
// BM=128, BN=64, BK=32, 256 thr (4 waves, 2x2 -> 64x32 per wave, acc[4][2]).
// Double-buffered LDS + 2-phase prefetch: stage(next) issued after the
// barrier, before compute(cur); ONE __syncthreads per K-step (its implicit
// vmcnt(0) drain makes the prefetched tile ready). No atomics anywhere:
// residual handled as plain per-element read-add-write (single writer).
// fp32-B path stages via XOR-swizzled 16B chunks (p = c ^ (row&7)) exactly
// as the proven round-1 layout; bf16-B uses the m97 A-tile layout directly.
// ---------------------------------------------------------------------------
template<bool GELU, bool RES, bool OUTBF, bool BF16B>
__device__ __forceinline__
void gemm2_body(const bf16_t* __restrict__ A, const void* __restrict__ Bv,
                const float* __restrict__ bias, const float* __restrict__ Res,
                void* __restrict__ Cout, int M, int N, int K)
{
    constexpr int BSZ = BF16B ? 4096 : 8192;          // B buffer bytes
    __shared__ __align__(16) bf16_t As[2][128 * 32];  // 2 x 8 KB
    __shared__ __align__(16) char   Bs[2][BSZ];       // 2 x (4|8) KB

    const int t = threadIdx.x;
    const int w = t >> 6, l = t & 63;
    const int wm = (w >> 1) * 64, wn = (w & 1) * 32;
    const int g = l >> 4, fr = l & 15, e = fr & 7;

    // A staging: rd in {0,1}: row = rd*64 + (t>>2), col = (t&3)*8 bf16
    const long aRow = (long)blockIdx.x * 128 + (t >> 2);
    const int  aCol = (t & 3) * 8;
    // B staging
    const bf16_t* Bb = (const bf16_t*)Bv;
    const float*  Bf = (const float*)Bv;
    const long bRow16 = (long)blockIdx.y * 64 + (t >> 2);   // bf16: row t>>2, col (t&3)*8
    const int  bCol16 = (t & 3) * 8;
    const long bRow32 = (long)blockIdx.y * 64 + (t >> 3);   // fp32: rd in {0,1}
    const int  bCol32 = (((t & 7) ^ ((t >> 3) & 7)) << 2);

    char* aW = (char*)As + w * 1024;
    char* bW = (char*)Bs + w * 1024;

    f32x4 acc[4][2] = {};
    const int nIter = K / 32;

    auto STAGE = [&](int k0, int buf) {
        load_lds16(A + aRow * K + (k0 + aCol),        aW + buf * 8192);
        load_lds16(A + (aRow + 64) * K + (k0 + aCol), aW + buf * 8192 + 4096);
        if (BF16B) {
            load_lds16(Bb + bRow16 * K + (k0 + bCol16), bW + buf * 4096);
        } else {
            load_lds16(Bf + bRow32 * (long)K + (k0 + bCol32),        bW + buf * 8192);
            load_lds16(Bf + (bRow32 + 32) * (long)K + (k0 + bCol32), bW + buf * 8192 + 4096);
        }
    };

    STAGE(0, 0);
    int buf = 0;
    for (int it = 0; it < nIter; ++it) {
        __syncthreads();                         // drains prefetch (vmcnt0) + sync
        if (it + 1 < nIter) STAGE((it + 1) * 32, buf ^ 1);

        const char* ab = (const char*)As + buf * 8192;
        const char* bb = (const char*)Bs + buf * BSZ;
        bf16x8 af[4], bfr[2];
        #pragma unroll
        for (int mi = 0; mi < 4; ++mi)
            af[mi] = *(const bf16x8*)(ab + (wm + mi * 16 + fr) * 64 + g * 16);
        if (BF16B) {
            #pragma unroll
            for (int ni = 0; ni < 2; ++ni)
                bfr[ni] = *(const bf16x8*)(bb + (wn + ni * 16 + fr) * 64 + g * 16);
        } else {
            #pragma unroll
            for (int ni = 0; ni < 2; ++ni) {
                const char* rp = bb + (wn + ni * 16 + fr) * 128;
                f32x4 lo = *(const f32x4*)(rp + (((2 * g)     ^ e) << 4));
                f32x4 hi = *(const f32x4*)(rp + (((2 * g + 1) ^ e) << 4));
                bf16x8 bbv;
                #pragma unroll
                for (int j = 0; j < 4; ++j) { bbv[j] = (bf16_t)lo[j]; bbv[4 + j] = (bf16_t)hi[j]; }
                bfr[ni] = bbv;
            }
        }
        #pragma unroll
        for (int mi = 0; mi < 4; ++mi)
            #pragma unroll
            for (int ni = 0; ni < 2; ++ni)
                acc[mi][ni] = __builtin_amdgcn_mfma_f32_16x16x32_bf16(
                    af[mi], bfr[ni], acc[mi][ni], 0, 0, 0);
        buf ^= 1;
    }

    // epilogue: C/D layout col = l&15, row = (l>>4)*4 + reg
    bf16_t* Cb = (bf16_t*)Cout;
    float*  Cf = (float*)Cout;
    const int r0 = g * 4;
    #pragma unroll
    for (int ni = 0; ni < 2; ++ni) {
        const int gc = blockIdx.y * 64 + wn + ni * 16 + fr;
        const float bv = bias[gc];
        #pragma unroll
        for (int mi = 0; mi < 4; ++mi) {
            #pragma unroll
            for (int r = 0; r < 4; ++r) {
                const long gr = (long)blockIdx.x * 128 + wm + mi * 16 + r0 + r;
                float vv = acc[mi][ni][r] + bv;
                if (GELU) vv = gelu_f(vv);
                if (RES)  vv += Res[gr * N + gc];
                if (OUTBF) Cb[gr * N + gc] = (bf16_t)vv;
                else       Cf[gr * N + gc] = vv;
            }
        }
    }
}

template<bool GELU, bool RES, bool OUTBF, bool BF16B>
__global__ __launch_bounds__(256, 2)
void gemm2_kernel(const bf16_t* __restrict__ A, const void* __restrict__ B,
                  const float* __restrict__ bias, const float* Res,
                  void* Cout, int M, int N, int K)
{
    gemm2_body<GELU, RES, OUTBF, BF16B>(A, B, bias, Res, Cout, M, N, K);
}

// Fused Q/K/V projection (bf16 weights): grid.z selects weight/bias/output.
__global__ __launch_bounds__(256, 2)
void qkv2_kernel(const bf16_t* __restrict__ A,
                 const bf16_t* __restrict__ B0, const bf16_t* __restrict__ B1,
                 const bf16_t* __restrict__ B2,
                 const float* __restrict__ b0, const float* __restrict__ b1,
                 const float* __restrict__ b2,
                 bf16_t* C0, bf16_t* C1, bf16_t* C2, int M, int N, int K)
{
    const int z = blockIdx.z;
    const bf16_t* B    = (z == 0) ? B0 : (z == 1) ? B1 : B2;
    const float*  bias = (z == 0) ? b0 : (z == 1) ? b1 : b2;
    bf16_t*       C    = (z == 0) ? C0 : (z == 1) ? C1 : C2;
    gemm2_body<false, false, true, true>(A, B, bias, nullptr, C, M, N, K);
}

// ---------------------------------------------------------------------------
// LayerNorm over D=1024: fp32 in -> bf16 out. One 256-thr block per token.
// ---------------------------------------------------------------------------
__global__ __launch_bounds__(256)
void ln_kernel(const float* __restrict__ in, const float* __restrict__ w,
               const float* __restrict__ b, bf16_t* __restrict__ out)
{
    const long row = blockIdx.x;
    const int t = threadIdx.x;
    f32x4 xv = *(const f32x4*)(in + row * DMODEL + t * 4);
    float s  = xv[0] + xv[1] + xv[2] + xv[3];
    float ss = xv[0]*xv[0] + xv[1]*xv[1] + xv[2]*xv[2] + xv[3]*xv[3];
    #pragma unroll
    for (int off = 32; off; off >>= 1) {
        s  += __shfl_xor(s, off);
        ss += __shfl_xor(ss, off);
    }
    __shared__ float sbuf[4], ssbuf[4];
    if ((t & 63) == 0) { sbuf[t >> 6] = s; ssbuf[t >> 6] = ss; }
    __syncthreads();
    s  = sbuf[0] + sbuf[1] + sbuf[2] + sbuf[3];
    ss = ssbuf[0] + ssbuf[1] + ssbuf[2] + ssbuf[3];
    const float mean = s * (1.f / DMODEL);
    const float var  = ss * (1.f / DMODEL) - mean * mean;
    const float rstd = rsqrtf(var + 1e-5f);
    f32x4 wv = *(const f32x4*)(w + t * 4);
    f32x4 bv = *(const f32x4*)(b + t * 4);
    bf16x4 o4;
    #pragma unroll
    for (int j = 0; j < 4; ++j)
        o4[j] = (bf16_t)((xv[j] - mean) * rstd * wv[j] + bv[j]);
    *(bf16x4*)(out + row * DMODEL + t * 4) = o4;
}

// ---------------------------------------------------------------------------
// Flash attention (non-causal, mask==0): block = (b,h, 64 q rows), 4 waves,
// wave w owns q rows [16w,16w+16). bf16 MFMA 16x16x32, fp32 online softmax.
// K/V tiles (64s x 64d) staged per step; V stored transposed [d][s].
// Q/K/V LDS rows XOR-swizzled in 16B chunks (p = c ^ (row&7)) -> 2-way banks.
// P round-trips through per-wave LDS (C-layout -> A-layout), m120 pattern.
// Grid MUST be B*H*(T/64) = 1024 blocks.
// ---------------------------------------------------------------------------
__global__ __launch_bounds__(256)
void attn_kernel(const bf16_t* __restrict__ q, const bf16_t* __restrict__ k,
                 const bf16_t* __restrict__ v, bf16_t* __restrict__ o)
{
    __shared__ bf16_t Qs[64 * 64], Ks[64 * 64], Vs[64 * 64];
    __shared__ bf16_t Ps[4][16 * 64];
    const int t = threadIdx.x, w = t >> 6, l = t & 63;
    const int g = l >> 4, fr = l & 15, e = fr & 7;
    const int qblk = blockIdx.x & 15, bh = blockIdx.x >> 4;   // bh in 0..63
    const int b = bh >> 4, h = bh & 15;
    const long base = (long)b * TSEQ * DMODEL + h * HDIM;

    // staging map: row = t>>2 (64 rows), 16B-chunk pair c2, c2+1
    const int sr = t >> 2, c2 = (t & 3) * 2;
    const int p0 = c2 ^ (sr & 7), p1 = (c2 + 1) ^ (sr & 7);
    const int s7 = sr & 7, scs = sr >> 3;

    {   // stage Q once
        const bf16_t* qg = q + base + (long)(qblk * 64 + sr) * DMODEL + c2 * 8;
        bf16x8 a0 = *(const bf16x8*)qg, a1 = *(const bf16x8*)(qg + 8);
        *(bf16x8*)((char*)Qs + sr * 128 + p0 * 16) = a0;
        *(bf16x8*)((char*)Qs + sr * 128 + p1 * 16) = a1;
    }
    __syncthreads();
    bf16x8 qf[2];
    {
        const char* qp = (const char*)Qs + (16 * w + fr) * 128;
        qf[0] = *(const bf16x8*)(qp + ((g       ^ e) << 4));
        qf[1] = *(const bf16x8*)(qp + (((g + 4) ^ e) << 4));
    }

    float m_[4], lsum[4] = {0.f, 0.f, 0.f, 0.f};
    #pragma unroll
    for (int r = 0; r < 4; ++r) m_[r] = -1e30f;
    f32x4 oacc[4] = {};

    for (int s0 = 0; s0 < TSEQ; s0 += 64) {
        __syncthreads();
        {   // stage K tile
            const bf16_t* kg = k + base + (long)(s0 + sr) * DMODEL + c2 * 8;
            bf16x8 a0 = *(const bf16x8*)kg, a1 = *(const bf16x8*)(kg + 8);
            *(bf16x8*)((char*)Ks + sr * 128 + p0 * 16) = a0;
            *(bf16x8*)((char*)Ks + sr * 128 + p1 * 16) = a1;
        }
        {   // stage V transposed: thread loads V[s=sr][d0..d0+16), scatters to Vs[d][s]
            const bf16_t* vg = v + base + (long)(s0 + sr) * DMODEL + (t & 3) * 16;
            bf16x8 v0 = *(const bf16x8*)vg, v1 = *(const bf16x8*)(vg + 8);
            #pragma unroll
            for (int u = 0; u < 8; ++u) {
                int d0 = (t & 3) * 16 + u;
                ((bf16_t*)((char*)Vs + d0 * 128 + ((scs ^ (d0 & 7)) << 4)))[s7] = v0[u];
                int d1 = d0 + 8;
                ((bf16_t*)((char*)Vs + d1 * 128 + ((scs ^ (d1 & 7)) << 4)))[s7] = v1[u];
            }
        }
        __syncthreads();

        // S = Q K^T  (4 s-subtiles x 2 k-steps)
        f32x4 sacc[4] = {};
        #pragma unroll
        for (int ni = 0; ni < 4; ++ni) {
            const char* kp = (const char*)Ks + (ni * 16 + fr) * 128;
            bf16x8 kf0 = *(const bf16x8*)(kp + ((g       ^ e) << 4));
            bf16x8 kf1 = *(const bf16x8*)(kp + (((g + 4) ^ e) << 4));
            sacc[ni] = __builtin_amdgcn_mfma_f32_16x16x32_bf16(qf[0], kf0, sacc[ni], 0, 0, 0);
            sacc[ni] = __builtin_amdgcn_mfma_f32_16x16x32_bf16(qf[1], kf1, sacc[ni], 0, 0, 0);
        }

        // online softmax; S row = g*4 + r (local q), col = ni*16 + fr (local s)
        #pragma unroll
        for (int r = 0; r < 4; ++r) {
            float a = fmaxf(fmaxf(sacc[0][r], sacc[1][r]),
                            fmaxf(sacc[2][r], sacc[3][r])) * 0.125f;
            #pragma unroll
            for (int off = 1; off < 16; off <<= 1) a = fmaxf(a, __shfl_xor(a, off));
            float mnew  = fmaxf(m_[r], a);
            float alpha = __expf(m_[r] - mnew);
            m_[r] = mnew;
            float sum = 0.f;
            #pragma unroll
            for (int ni = 0; ni < 4; ++ni) {
                float p = __expf(sacc[ni][r] * 0.125f - mnew);
                sum += p;
                Ps[w][(g * 4 + r) * 64 + ni * 16 + fr] = (bf16_t)p;
            }
            #pragma unroll
            for (int off = 1; off < 16; off <<= 1) sum += __shfl_xor(sum, off);
            lsum[r] = lsum[r] * alpha + sum;
            #pragma unroll
            for (int di = 0; di < 4; ++di) oacc[di][r] *= alpha;
        }

        // O += P V   (P: A-layout from per-wave LDS; V^T rows, swizzled)
        bf16x8 pf0 = *(const bf16x8*)&Ps[w][fr * 64 + g * 8];
        bf16x8 pf1 = *(const bf16x8*)&Ps[w][fr * 64 + 32 + g * 8];
        #pragma unroll
        for (int di = 0; di < 4; ++di) {
            const char* vp = (const char*)Vs + (di * 16 + fr) * 128;
            bf16x8 vf0 = *(const bf16x8*)(vp + ((g       ^ e) << 4));
            bf16x8 vf1 = *(const bf16x8*)(vp + (((g + 4) ^ e) << 4));
            oacc[di] = __builtin_amdgcn_mfma_f32_16x16x32_bf16(pf0, vf0, oacc[di], 0, 0, 0);
            oacc[di] = __builtin_amdgcn_mfma_f32_16x16x32_bf16(pf1, vf1, oacc[di], 0, 0, 0);
        }
    }

    #pragma unroll
    for (int r = 0; r < 4; ++r) {
        const float inv = 1.f / lsum[r];
        const long tq = qblk * 64 + 16 * w + g * 4 + r;
        #pragma unroll
        for (int di = 0; di < 4; ++di)
            o[base + tq * DMODEL + di * 16 + fr] = (bf16_t)(oacc[di][r] * inv);
    }
}

// ---------------------------------------------------------------------------
extern "C" void kernel_launch(void* const* d_in, const int* in_sizes, int n_in,
                              void* d_out, int out_size, void* d_ws, size_t ws_size,
                              hipStream_t stream)
{
    const float* hs    = (const float*)d_in[0];
    const float* ln1w  = (const float*)d_in[2];
    const float* ln1b  = (const float*)d_in[3];
    const float* qw    = (const float*)d_in[4];
    const float* qbias = (const float*)d_in[5];
    const float* kw    = (const float*)d_in[6];
    const float* kbias = (const float*)d_in[7];
    const float* vw    = (const float*)d_in[8];
    const float* vbias = (const float*)d_in[9];
    const float* ow    = (const float*)d_in[10];
    const float* obias = (const float*)d_in[11];
    const float* ln2w  = (const float*)d_in[12];
    const float* ln2b  = (const float*)d_in[13];
    const float* fc1w  = (const float*)d_in[14];
    const float* fc1b  = (const float*)d_in[15];
    const float* fc2w  = (const float*)d_in[16];
    const float* fc2b  = (const float*)d_in[17];
    const float* lnpw  = (const float*)d_in[18];
    const float* lnpb  = (const float*)d_in[19];
    const float* p1w   = (const float*)d_in[20];
    const float* p1b   = (const float*)d_in[21];
    const float* p2w   = (const float*)d_in[22];
    const float* p2b   = (const float*)d_in[23];

    // ws (56 MB): h fp32 [0,16) | x bf16 [16,24) | q [24,32) | k [32,40)
    //             | v [40,48) | tail [48,56)
    // Dead-window reuse for bf16 weights:
    //   qkv weights -> tail   (free between fc2(i-1) and fc1(i))
    //   ow          -> qbuf   (free after attn(i), until fc1(i))
    //   fc2w        -> x      (free after fc1(i) consumed x)
    //   p1w -> kbuf, p2w -> vbuf (free after final fc2)
    float*  h    = (float*)d_ws;
    bf16_t* x    = (bf16_t*)(h + (long)NTOK * DMODEL);
    bf16_t* qbuf = x    + (long)NTOK * DMODEL;
    bf16_t* kbuf = qbuf + (long)NTOK * DMODEL;
    bf16_t* vbuf = kbuf + (long)NTOK * DMODEL;
    bf16_t* tail = vbuf + (long)NTOK * DMODEL;
    bf16_t* obuf = x;      // x dead after V-proj; attention writes o here
    bf16_t* fbuf = qbuf;   // fc1 out: 32 MB spans q,k,v,tail

    bf16_t* qw16  = tail;                       // 3 x 1M elems (6 MB)
    bf16_t* kw16  = tail + (long)DMODEL * DMODEL;
    bf16_t* vw16  = kw16 + (long)DMODEL * DMODEL;
    bf16_t* ow16  = qbuf;                       // 2 MB in dead qbuf
    bf16_t* fc2w16 = x;                         // 8 MB exact fit in dead x
    bf16_t* p1w16 = kbuf;                       // 2 MB
    bf16_t* p2w16 = vbuf;                       // 4 MB

    hipMemcpyAsync(h, hs, (size_t)NTOK * DMODEL * sizeof(float),
                   hipMemcpyDeviceToDevice, stream);

    const dim3 blk(256);
    const dim3 gD(NTOK / 128, DMODEL / 64);         // N=1024: 32x16 = 512 blocks
    const dim3 gQKV(NTOK / 128, DMODEL / 64, 3);    // 1536 blocks
    const dim3 gF1(NTOK / 128, FDIM / 64);          // N=4096: 2048 blocks
    const dim3 gOut(NTOK / 128, OUTDIM / 64);       // N=2048: 1024 blocks
    const int  gAttn = (NTOK / 64) * NHEAD;         // 1024 blocks
    const int  cvtD  = (DMODEL * DMODEL) / 2048;    // 512 blocks per 1M elems

    for (int i = 0; i < NLAYER; ++i) {
        const long wD = (long)i * DMODEL * DMODEL;
        const long wF = (long)i * FDIM * DMODEL;
        // qkv weights -> bf16 in tail (tail free until fc1 writes fbuf)
        cvt3_kernel<<<dim3(cvtD, 1, 3), blk, 0, stream>>>(
            qw + wD, kw + wD, vw + wD, qw16, kw16, vw16);
        ln_kernel<<<NTOK, blk, 0, stream>>>(h, ln1w + i * DMODEL, ln1b + i * DMODEL, x);
        qkv2_kernel<<<gQKV, blk, 0, stream>>>(x, qw16, kw16, vw16,
                                              qbias + i * DMODEL, kbias + i * DMODEL, vbias + i * DMODEL,
                                              qbuf, kbuf, vbuf, NTOK, DMODEL, DMODEL);
        attn_kernel<<<gAttn, blk, 0, stream>>>(qbuf, kbuf, vbuf, obuf);
        // ow -> bf16 in dead qbuf; h += obuf @ ow^T + ob (plain RMW, no atomics)
        cvt_kernel<<<cvtD, blk, 0, stream>>>(ow + wD, ow16);
        gemm2_kernel<false, true, false, true><<<gD, blk, 0, stream>>>(
            obuf, ow16, obias + i * DMODEL, h, h, NTOK, DMODEL, DMODEL);
        ln_kernel<<<NTOK, blk, 0, stream>>>(h, ln2w + i * DMODEL, ln2b + i * DMODEL, x);
        gemm2_kernel<true, false, true, false><<<gF1, blk, 0, stream>>>(
            x, fc1w + wF, fc1b + (long)i * FDIM, nullptr, fbuf, NTOK, FDIM, DMODEL);
        // fc2w -> bf16 in x (x consumed by fc1); h += fbuf @ fc2w^T + fc2b
        cvt_kernel<<<cvtD * 4, blk, 0, stream>>>(fc2w + wF, fc2w16);
        gemm2_kernel<false, true, false, true><<<gD, blk, 0, stream>>>(
            fbuf, fc2w16, fc2b + i * DMODEL, h, h, NTOK, DMODEL, FDIM);
    }

    ln_kernel<<<NTOK, blk, 0, stream>>>(h, lnpw, lnpb, x);
    cvt_kernel<<<cvtD, blk, 0, stream>>>(p1w, p1w16);
    gemm2_kernel<true, false, true, true><<<gD, blk, 0, stream>>>(
        x, p1w16, p1b, nullptr, qbuf, NTOK, DMODEL, DMODEL);
    cvt_kernel<<<cvtD * 2, blk, 0, stream>>>(p2w, p2w16);
    gemm2_kernel<false, false, false, true><<<gOut, blk, 0, stream>>>(
        qbuf, p2w16, p2b, nullptr, d_out, NTOK, OUTDIM, DMODEL);
}

// Round 4
// 2055.545 us; speedup vs baseline: 1.5290x; 1.0844x over previous
//
#include <hip/hip_runtime.h>
#include <hip/hip_bf16.h>

typedef __bf16 bf16_t;
typedef __bf16 bf16x8 __attribute__((ext_vector_type(8)));
typedef __bf16 bf16x4 __attribute__((ext_vector_type(4)));
typedef float  f32x4  __attribute__((ext_vector_type(4)));

#define NTOK   4096   // B*T
#define DMODEL 1024
#define NHEAD  16
#define HDIM   64
#define TSEQ   1024
#define FDIM   4096
#define NLAYER 6
#define OUTDIM 2048

__device__ __forceinline__ float gelu_f(float x) {
    const float c = 0.7978845608028654f;  // sqrt(2/pi)
    float u = c * (x + 0.044715f * x * x * x);
    return 0.5f * x * (1.0f + tanhf(u));
}

__device__ __forceinline__ void load_lds16(const void* g, void* l) {
    __builtin_amdgcn_global_load_lds(
        (const __attribute__((address_space(1))) void*)g,
        (__attribute__((address_space(3))) void*)l, 16, 0, 0);
}

// ---------------------------------------------------------------------------
// fp32 -> bf16 weight conversion (RNE, identical numerics to in-loop cast).
// 8 elems / thread, exact grid.
// ---------------------------------------------------------------------------
__global__ __launch_bounds__(256)
void cvt_kernel(const float* __restrict__ in, bf16_t* __restrict__ out)
{
    const long i = ((long)blockIdx.x * 256 + threadIdx.x) * 8;
    f32x4 a = *(const f32x4*)(in + i);
    f32x4 b = *(const f32x4*)(in + i + 4);
    bf16x8 o;
    #pragma unroll
    for (int j = 0; j < 4; ++j) { o[j] = (bf16_t)a[j]; o[4 + j] = (bf16_t)b[j]; }
    *(bf16x8*)(out + i) = o;
}

// 3-tensor variant (q/k/v weights) — one launch, grid.z selects tensor.
__global__ __launch_bounds__(256)
void cvt3_kernel(const float* __restrict__ i0, const float* __restrict__ i1,
                 const float* __restrict__ i2, bf16_t* __restrict__ o0,
                 bf16_t* __restrict__ o1, bf16_t* __restrict__ o2)
{
    const float* in  = (blockIdx.z == 0) ? i0 : (blockIdx.z == 1) ? i1 : i2;
    bf16_t*      out = (blockIdx.z == 0) ? o0 : (blockIdx.z == 1) ? o1 : o2;
    const long i = ((long)blockIdx.x * 256 + threadIdx.x) * 8;
    f32x4 a = *(const f32x4*)(in + i);
    f32x4 b = *(const f32x4*)(in + i + 4);
    bf16x8 o;
    #pragma unroll
    for (int j = 0; j < 4; ++j) { o[j] = (bf16_t)a[j]; o[4 + j] = (bf16_t)b[j]; }
    *(bf16x8*)(out + i) = o;
}

// ---------------------------------------------------------------------------
// GEMM v3: C[M,N] = A[M,K](bf16) @ B[N,K](bf16)^T + bias(fp32).
// BM=128, BN in {64,128}, BK=32, 256 thr, 4 waves 2x2.
//   BN=64 : per-wave 64x32, acc[4][2] (N=1024 GEMMs, grid 512 = 2 blk/CU)
//   BN=128: per-wave 64x64, acc[4][4] (fc1/p2, more reuse per LDS byte)
// Double-buffered LDS + 2-phase prefetch (stage(next) after barrier, before
// compute(cur); ONE __syncthreads per K-step whose implicit vmcnt(0) drain
// publishes the prefetch). 4-chunk XOR swizzle on ALL tiles: global source
// column pre-swizzled (chunk c ^ (row&3)) so the linear global_load_lds dest
// holds swizzled data; reads XOR with fr&3 -> 4-way banks instead of 8-way.
// Residual = plain RMW (single writer), no atomics.
// ---------------------------------------------------------------------------
template<bool GELU, bool RES, bool OUTBF, int BN>
__device__ __forceinline__
void gemm3_body(const bf16_t* __restrict__ A, const bf16_t* __restrict__ B,
                const float* __restrict__ bias, const float* __restrict__ Res,
                void* __restrict__ Cout, int M, int N, int K)
{
    constexpr int NI  = BN / 32;          // n-subtiles per wave
    constexpr int BBY = BN * 64;          // B tile bytes per buffer
    __shared__ __align__(16) bf16_t As[2][128 * 32];   // 2 x 8 KB
    __shared__ __align__(16) char   Bs[2][BBY];        // 2 x (4|8) KB

    const int t = threadIdx.x;
    const int w = t >> 6, l = t & 63;
    const int wm = (w >> 1) * 64, wn = (w & 1) * (BN / 2);
    const int g = l >> 4, fr = l & 15, e2 = fr & 3;

    // staging: row = t>>2 (+64 for round 2), 16B chunk t&3; source column
    // pre-swizzled: chunk (t&3) ^ (row&3)  (row&3 == (t>>2)&3, both rounds)
    const int  sCol = (((t & 3) ^ ((t >> 2) & 3)) << 3);  // bf16 elems
    const long aRow = (long)blockIdx.x * 128 + (t >> 2);
    const long bRow = (long)blockIdx.y * BN  + (t >> 2);

    char* aW = (char*)As + w * 1024;
    char* bW = (char*)Bs + w * 1024;

    f32x4 acc[4][NI] = {};
    const int nIter = K / 32;

    auto STAGE = [&](int k0, int buf) {
        load_lds16(A + aRow * K + (k0 + sCol),        aW + buf * 8192);
        load_lds16(A + (aRow + 64) * K + (k0 + sCol), aW + buf * 8192 + 4096);
        if (BN == 128) {
            load_lds16(B + bRow * K + (k0 + sCol),        bW + buf * BBY);
            load_lds16(B + (bRow + 64) * K + (k0 + sCol), bW + buf * BBY + 4096);
        } else {
            load_lds16(B + bRow * K + (k0 + sCol), bW + buf * BBY);
        }
    };

    STAGE(0, 0);
    int buf = 0;
    for (int it = 0; it < nIter; ++it) {
        __syncthreads();                         // drains prefetch (vmcnt0) + sync
        if (it + 1 < nIter) STAGE((it + 1) * 32, buf ^ 1);

        const char* ab = (const char*)As + buf * 8192;
        const char* bb = (const char*)Bs + buf * BBY;
        bf16x8 af[4], bfr[NI];
        #pragma unroll
        for (int mi = 0; mi < 4; ++mi)
            af[mi] = *(const bf16x8*)(ab + (wm + mi * 16 + fr) * 64 + ((g ^ e2) << 4));
        #pragma unroll
        for (int ni = 0; ni < NI; ++ni)
            bfr[ni] = *(const bf16x8*)(bb + (wn + ni * 16 + fr) * 64 + ((g ^ e2) << 4));
        #pragma unroll
        for (int mi = 0; mi < 4; ++mi)
            #pragma unroll
            for (int ni = 0; ni < NI; ++ni)
                acc[mi][ni] = __builtin_amdgcn_mfma_f32_16x16x32_bf16(
                    af[mi], bfr[ni], acc[mi][ni], 0, 0, 0);
        buf ^= 1;
    }

    // epilogue: C/D layout col = l&15, row = (l>>4)*4 + reg
    bf16_t* Cb = (bf16_t*)Cout;
    float*  Cf = (float*)Cout;
    const int r0 = g * 4;
    #pragma unroll
    for (int ni = 0; ni < NI; ++ni) {
        const int gc = blockIdx.y * BN + wn + ni * 16 + fr;
        const float bv = bias[gc];
        #pragma unroll
        for (int mi = 0; mi < 4; ++mi) {
            #pragma unroll
            for (int r = 0; r < 4; ++r) {
                const long gr = (long)blockIdx.x * 128 + wm + mi * 16 + r0 + r;
                float vv = acc[mi][ni][r] + bv;
                if (GELU) vv = gelu_f(vv);
                if (RES)  vv += Res[gr * N + gc];
                if (OUTBF) Cb[gr * N + gc] = (bf16_t)vv;
                else       Cf[gr * N + gc] = vv;
            }
        }
    }
}

template<bool GELU, bool RES, bool OUTBF, int BN>
__global__ __launch_bounds__(256, 2)
void gemm3_kernel(const bf16_t* __restrict__ A, const bf16_t* __restrict__ B,
                  const float* __restrict__ bias, const float* Res,
                  void* Cout, int M, int N, int K)
{
    gemm3_body<GELU, RES, OUTBF, BN>(A, B, bias, Res, Cout, M, N, K);
}

// Fused Q/K/V projection (bf16 weights): grid.z selects weight/bias/output.
__global__ __launch_bounds__(256, 2)
void qkv3_kernel(const bf16_t* __restrict__ A,
                 const bf16_t* __restrict__ B0, const bf16_t* __restrict__ B1,
                 const bf16_t* __restrict__ B2,
                 const float* __restrict__ b0, const float* __restrict__ b1,
                 const float* __restrict__ b2,
                 bf16_t* C0, bf16_t* C1, bf16_t* C2, int M, int N, int K)
{
    const int z = blockIdx.z;
    const bf16_t* B    = (z == 0) ? B0 : (z == 1) ? B1 : B2;
    const float*  bias = (z == 0) ? b0 : (z == 1) ? b1 : b2;
    bf16_t*       C    = (z == 0) ? C0 : (z == 1) ? C1 : C2;
    gemm3_body<false, false, true, 64>(A, B, bias, nullptr, C, M, N, K);
}

// ---------------------------------------------------------------------------
// LayerNorm over D=1024: fp32 in -> bf16 out. One 256-thr block per token.
// ---------------------------------------------------------------------------
__global__ __launch_bounds__(256)
void ln_kernel(const float* __restrict__ in, const float* __restrict__ w,
               const float* __restrict__ b, bf16_t* __restrict__ out)
{
    const long row = blockIdx.x;
    const int t = threadIdx.x;
    f32x4 xv = *(const f32x4*)(in + row * DMODEL + t * 4);
    float s  = xv[0] + xv[1] + xv[2] + xv[3];
    float ss = xv[0]*xv[0] + xv[1]*xv[1] + xv[2]*xv[2] + xv[3]*xv[3];
    #pragma unroll
    for (int off = 32; off; off >>= 1) {
        s  += __shfl_xor(s, off);
        ss += __shfl_xor(ss, off);
    }
    __shared__ float sbuf[4], ssbuf[4];
    if ((t & 63) == 0) { sbuf[t >> 6] = s; ssbuf[t >> 6] = ss; }
    __syncthreads();
    s  = sbuf[0] + sbuf[1] + sbuf[2] + sbuf[3];
    ss = ssbuf[0] + ssbuf[1] + ssbuf[2] + ssbuf[3];
    const float mean = s * (1.f / DMODEL);
    const float var  = ss * (1.f / DMODEL) - mean * mean;
    const float rstd = rsqrtf(var + 1e-5f);
    f32x4 wv = *(const f32x4*)(w + t * 4);
    f32x4 bv = *(const f32x4*)(b + t * 4);
    bf16x4 o4;
    #pragma unroll
    for (int j = 0; j < 4; ++j)
        o4[j] = (bf16_t)((xv[j] - mean) * rstd * wv[j] + bv[j]);
    *(bf16x4*)(out + row * DMODEL + t * 4) = o4;
}

// ---------------------------------------------------------------------------
// Flash attention (non-causal, mask==0): block = (b,h, 64 q rows), 4 waves,
// wave w owns q rows [16w,16w+16). bf16 MFMA 16x16x32, fp32 online softmax.
// K/V tiles (64s x 64d) staged per step; V stored transposed [d][s].
// Q/K/V LDS rows XOR-swizzled in 16B chunks (p = c ^ (row&7)) -> 2-way banks.
// P round-trips through per-wave LDS (C-layout -> A-layout), m120 pattern.
// Grid MUST be B*H*(T/64) = 1024 blocks.
// ---------------------------------------------------------------------------
__global__ __launch_bounds__(256)
void attn_kernel(const bf16_t* __restrict__ q, const bf16_t* __restrict__ k,
                 const bf16_t* __restrict__ v, bf16_t* __restrict__ o)
{
    __shared__ bf16_t Qs[64 * 64], Ks[64 * 64], Vs[64 * 64];
    __shared__ bf16_t Ps[4][16 * 64];
    const int t = threadIdx.x, w = t >> 6, l = t & 63;
    const int g = l >> 4, fr = l & 15, e = fr & 7;
    const int qblk = blockIdx.x & 15, bh = blockIdx.x >> 4;   // bh in 0..63
    const int b = bh >> 4, h = bh & 15;
    const long base = (long)b * TSEQ * DMODEL + h * HDIM;

    // staging map: row = t>>2 (64 rows), 16B-chunk pair c2, c2+1
    const int sr = t >> 2, c2 = (t & 3) * 2;
    const int p0 = c2 ^ (sr & 7), p1 = (c2 + 1) ^ (sr & 7);
    const int s7 = sr & 7, scs = sr >> 3;

    {   // stage Q once
        const bf16_t* qg = q + base + (long)(qblk * 64 + sr) * DMODEL + c2 * 8;
        bf16x8 a0 = *(const bf16x8*)qg, a1 = *(const bf16x8*)(qg + 8);
        *(bf16x8*)((char*)Qs + sr * 128 + p0 * 16) = a0;
        *(bf16x8*)((char*)Qs + sr * 128 + p1 * 16) = a1;
    }
    __syncthreads();
    bf16x8 qf[2];
    {
        const char* qp = (const char*)Qs + (16 * w + fr) * 128;
        qf[0] = *(const bf16x8*)(qp + ((g       ^ e) << 4));
        qf[1] = *(const bf16x8*)(qp + (((g + 4) ^ e) << 4));
    }

    float m_[4], lsum[4] = {0.f, 0.f, 0.f, 0.f};
    #pragma unroll
    for (int r = 0; r < 4; ++r) m_[r] = -1e30f;
    f32x4 oacc[4] = {};

    for (int s0 = 0; s0 < TSEQ; s0 += 64) {
        __syncthreads();
        {   // stage K tile
            const bf16_t* kg = k + base + (long)(s0 + sr) * DMODEL + c2 * 8;
            bf16x8 a0 = *(const bf16x8*)kg, a1 = *(const bf16x8*)(kg + 8);
            *(bf16x8*)((char*)Ks + sr * 128 + p0 * 16) = a0;
            *(bf16x8*)((char*)Ks + sr * 128 + p1 * 16) = a1;
        }
        {   // stage V transposed: thread loads V[s=sr][d0..d0+16), scatters to Vs[d][s]
            const bf16_t* vg = v + base + (long)(s0 + sr) * DMODEL + (t & 3) * 16;
            bf16x8 v0 = *(const bf16x8*)vg, v1 = *(const bf16x8*)(vg + 8);
            #pragma unroll
            for (int u = 0; u < 8; ++u) {
                int d0 = (t & 3) * 16 + u;
                ((bf16_t*)((char*)Vs + d0 * 128 + ((scs ^ (d0 & 7)) << 4)))[s7] = v0[u];
                int d1 = d0 + 8;
                ((bf16_t*)((char*)Vs + d1 * 128 + ((scs ^ (d1 & 7)) << 4)))[s7] = v1[u];
            }
        }
        __syncthreads();

        // S = Q K^T  (4 s-subtiles x 2 k-steps)
        f32x4 sacc[4] = {};
        #pragma unroll
        for (int ni = 0; ni < 4; ++ni) {
            const char* kp = (const char*)Ks + (ni * 16 + fr) * 128;
            bf16x8 kf0 = *(const bf16x8*)(kp + ((g       ^ e) << 4));
            bf16x8 kf1 = *(const bf16x8*)(kp + (((g + 4) ^ e) << 4));
            sacc[ni] = __builtin_amdgcn_mfma_f32_16x16x32_bf16(qf[0], kf0, sacc[ni], 0, 0, 0);
            sacc[ni] = __builtin_amdgcn_mfma_f32_16x16x32_bf16(qf[1], kf1, sacc[ni], 0, 0, 0);
        }

        // online softmax; S row = g*4 + r (local q), col = ni*16 + fr (local s)
        #pragma unroll
        for (int r = 0; r < 4; ++r) {
            float a = fmaxf(fmaxf(sacc[0][r], sacc[1][r]),
                            fmaxf(sacc[2][r], sacc[3][r])) * 0.125f;
            #pragma unroll
            for (int off = 1; off < 16; off <<= 1) a = fmaxf(a, __shfl_xor(a, off));
            float mnew  = fmaxf(m_[r], a);
            float alpha = __expf(m_[r] - mnew);
            m_[r] = mnew;
            float sum = 0.f;
            #pragma unroll
            for (int ni = 0; ni < 4; ++ni) {
                float p = __expf(sacc[ni][r] * 0.125f - mnew);
                sum += p;
                Ps[w][(g * 4 + r) * 64 + ni * 16 + fr] = (bf16_t)p;
            }
            #pragma unroll
            for (int off = 1; off < 16; off <<= 1) sum += __shfl_xor(sum, off);
            lsum[r] = lsum[r] * alpha + sum;
            #pragma unroll
            for (int di = 0; di < 4; ++di) oacc[di][r] *= alpha;
        }

        // O += P V   (P: A-layout from per-wave LDS; V^T rows, swizzled)
        bf16x8 pf0 = *(const bf16x8*)&Ps[w][fr * 64 + g * 8];
        bf16x8 pf1 = *(const bf16x8*)&Ps[w][fr * 64 + 32 + g * 8];
        #pragma unroll
        for (int di = 0; di < 4; ++di) {
            const char* vp = (const char*)Vs + (di * 16 + fr) * 128;
            bf16x8 vf0 = *(const bf16x8*)(vp + ((g       ^ e) << 4));
            bf16x8 vf1 = *(const bf16x8*)(vp + (((g + 4) ^ e) << 4));
            oacc[di] = __builtin_amdgcn_mfma_f32_16x16x32_bf16(pf0, vf0, oacc[di], 0, 0, 0);
            oacc[di] = __builtin_amdgcn_mfma_f32_16x16x32_bf16(pf1, vf1, oacc[di], 0, 0, 0);
        }
    }

    #pragma unroll
    for (int r = 0; r < 4; ++r) {
        const float inv = 1.f / lsum[r];
        const long tq = qblk * 64 + 16 * w + g * 4 + r;
        #pragma unroll
        for (int di = 0; di < 4; ++di)
            o[base + tq * DMODEL + di * 16 + fr] = (bf16_t)(oacc[di][r] * inv);
    }
}

// ---------------------------------------------------------------------------
extern "C" void kernel_launch(void* const* d_in, const int* in_sizes, int n_in,
                              void* d_out, int out_size, void* d_ws, size_t ws_size,
                              hipStream_t stream)
{
    const float* hs    = (const float*)d_in[0];
    const float* ln1w  = (const float*)d_in[2];
    const float* ln1b  = (const float*)d_in[3];
    const float* qw    = (const float*)d_in[4];
    const float* qbias = (const float*)d_in[5];
    const float* kw    = (const float*)d_in[6];
    const float* kbias = (const float*)d_in[7];
    const float* vw    = (const float*)d_in[8];
    const float* vbias = (const float*)d_in[9];
    const float* ow    = (const float*)d_in[10];
    const float* obias = (const float*)d_in[11];
    const float* ln2w  = (const float*)d_in[12];
    const float* ln2b  = (const float*)d_in[13];
    const float* fc1w  = (const float*)d_in[14];
    const float* fc1b  = (const float*)d_in[15];
    const float* fc2w  = (const float*)d_in[16];
    const float* fc2b  = (const float*)d_in[17];
    const float* lnpw  = (const float*)d_in[18];
    const float* lnpb  = (const float*)d_in[19];
    const float* p1w   = (const float*)d_in[20];
    const float* p1b   = (const float*)d_in[21];
    const float* p2w   = (const float*)d_in[22];
    const float* p2b   = (const float*)d_in[23];

    // ws (56 MB): h fp32 [0,16) | x bf16 [16,24) | q [24,32) | k [32,40)
    //             | v [40,48) | tail [48,56)
    // Dead-window reuse for bf16 weights:
    //   qkv weights -> tail   (free between fc2(i-1) and fc1(i))
    //   ow          -> qbuf   (free after attn(i), until fc1(i))
    //   fc1w        -> d_out  (32 MB fp32 output, only written by final GEMM)
    //   fc2w        -> x      (free after fc1(i) consumed x)
    //   p1w -> kbuf, p2w -> vbuf (free after final fc2)
    float*  h    = (float*)d_ws;
    bf16_t* x    = (bf16_t*)(h + (long)NTOK * DMODEL);
    bf16_t* qbuf = x    + (long)NTOK * DMODEL;
    bf16_t* kbuf = qbuf + (long)NTOK * DMODEL;
    bf16_t* vbuf = kbuf + (long)NTOK * DMODEL;
    bf16_t* tail = vbuf + (long)NTOK * DMODEL;
    bf16_t* obuf = x;      // x dead after V-proj; attention writes o here
    bf16_t* fbuf = qbuf;   // fc1 out: 32 MB spans q,k,v,tail

    bf16_t* qw16   = tail;                       // 3 x 1M elems (6 MB)
    bf16_t* kw16   = tail + (long)DMODEL * DMODEL;
    bf16_t* vw16   = kw16 + (long)DMODEL * DMODEL;
    bf16_t* ow16   = qbuf;                       // 2 MB in dead qbuf
    bf16_t* fc1w16 = (bf16_t*)d_out;             // 8 MB in dead d_out (32 MB)
    bf16_t* fc2w16 = x;                          // 8 MB exact fit in dead x
    bf16_t* p1w16  = kbuf;                       // 2 MB
    bf16_t* p2w16  = vbuf;                       // 4 MB

    hipMemcpyAsync(h, hs, (size_t)NTOK * DMODEL * sizeof(float),
                   hipMemcpyDeviceToDevice, stream);

    const dim3 blk(256);
    const dim3 gD(NTOK / 128, DMODEL / 64);          // N=1024, BN=64: 512 blocks
    const dim3 gQKV(NTOK / 128, DMODEL / 64, 3);     // 1536 blocks
    const dim3 gF1(NTOK / 128, FDIM / 128);          // N=4096, BN=128: 1024 blocks
    const dim3 gOut(NTOK / 128, OUTDIM / 128);       // N=2048, BN=128: 512 blocks
    const int  gAttn = (NTOK / 64) * NHEAD;          // 1024 blocks
    const int  cvtD  = (DMODEL * DMODEL) / 2048;     // 512 blocks per 1M elems

    for (int i = 0; i < NLAYER; ++i) {
        const long wD = (long)i * DMODEL * DMODEL;
        const long wF = (long)i * FDIM * DMODEL;
        // qkv weights -> bf16 in tail; fc1w -> bf16 in d_out
        cvt3_kernel<<<dim3(cvtD, 1, 3), blk, 0, stream>>>(
            qw + wD, kw + wD, vw + wD, qw16, kw16, vw16);
        cvt_kernel<<<cvtD * 4, blk, 0, stream>>>(fc1w + wF, fc1w16);
        ln_kernel<<<NTOK, blk, 0, stream>>>(h, ln1w + i * DMODEL, ln1b + i * DMODEL, x);
        qkv3_kernel<<<gQKV, blk, 0, stream>>>(x, qw16, kw16, vw16,
                                              qbias + i * DMODEL, kbias + i * DMODEL, vbias + i * DMODEL,
                                              qbuf, kbuf, vbuf, NTOK, DMODEL, DMODEL);
        attn_kernel<<<gAttn, blk, 0, stream>>>(qbuf, kbuf, vbuf, obuf);
        // ow -> bf16 in dead qbuf; h += obuf @ ow^T + ob (plain RMW)
        cvt_kernel<<<cvtD, blk, 0, stream>>>(ow + wD, ow16);
        gemm3_kernel<false, true, false, 64><<<gD, blk, 0, stream>>>(
            obuf, ow16, obias + i * DMODEL, h, h, NTOK, DMODEL, DMODEL);
        ln_kernel<<<NTOK, blk, 0, stream>>>(h, ln2w + i * DMODEL, ln2b + i * DMODEL, x);
        gemm3_kernel<true, false, true, 128><<<gF1, blk, 0, stream>>>(
            x, fc1w16, fc1b + (long)i * FDIM, nullptr, fbuf, NTOK, FDIM, DMODEL);
        // fc2w -> bf16 in x (x consumed by fc1); h += fbuf @ fc2w^T + fc2b
        cvt_kernel<<<cvtD * 4, blk, 0, stream>>>(fc2w + wF, fc2w16);
        gemm3_kernel<false, true, false, 64><<<gD, blk, 0, stream>>>(
            fbuf, fc2w16, fc2b + i * DMODEL, h, h, NTOK, DMODEL, FDIM);
    }

    ln_kernel<<<NTOK, blk, 0, stream>>>(h, lnpw, lnpb, x);
    cvt_kernel<<<cvtD, blk, 0, stream>>>(p1w, p1w16);
    gemm3_kernel<true, false, true, 64><<<gD, blk, 0, stream>>>(
        x, p1w16, p1b, nullptr, qbuf, NTOK, DMODEL, DMODEL);
    cvt_kernel<<<cvtD * 2, blk, 0, stream>>>(p2w, p2w16);
    gemm3_kernel<false, false, false, 128><<<gOut, blk, 0, stream>>>(
        qbuf, p2w16, p2b, nullptr, d_out, NTOK, OUTDIM, DMODEL);
}

// Round 5
// 2030.434 us; speedup vs baseline: 1.5479x; 1.0124x over previous
//
#include <hip/hip_runtime.h>
#include <hip/hip_bf16.h>

typedef __bf16 bf16_t;
typedef __bf16 bf16x8 __attribute__((ext_vector_type(8)));
typedef __bf16 bf16x4 __attribute__((ext_vector_type(4)));
typedef float  f32x4  __attribute__((ext_vector_type(4)));

#define NTOK   4096   // B*T
#define DMODEL 1024
#define NHEAD  16
#define HDIM   64
#define TSEQ   1024
#define FDIM   4096
#define NLAYER 6
#define OUTDIM 2048

__device__ __forceinline__ float gelu_f(float x) {
    const float c = 0.7978845608028654f;  // sqrt(2/pi)
    float u = c * (x + 0.044715f * x * x * x);
    return 0.5f * x * (1.0f + tanhf(u));
}

__device__ __forceinline__ void load_lds16(const void* g, void* l) {
    __builtin_amdgcn_global_load_lds(
        (const __attribute__((address_space(1))) void*)g,
        (__attribute__((address_space(3))) void*)l, 16, 0, 0);
}

// ---------------------------------------------------------------------------
// fp32 -> bf16 weight conversion (RNE, identical numerics to in-loop cast).
// ---------------------------------------------------------------------------
__global__ __launch_bounds__(256)
void cvt_kernel(const float* __restrict__ in, bf16_t* __restrict__ out)
{
    const long i = ((long)blockIdx.x * 256 + threadIdx.x) * 8;
    f32x4 a = *(const f32x4*)(in + i);
    f32x4 b = *(const f32x4*)(in + i + 4);
    bf16x8 o;
    #pragma unroll
    for (int j = 0; j < 4; ++j) { o[j] = (bf16_t)a[j]; o[4 + j] = (bf16_t)b[j]; }
    *(bf16x8*)(out + i) = o;
}

// 3-tensor variant (q/k/v weights) — one launch, grid.z selects tensor.
__global__ __launch_bounds__(256)
void cvt3_kernel(const float* __restrict__ i0, const float* __restrict__ i1,
                 const float* __restrict__ i2, bf16_t* __restrict__ o0,
                 bf16_t* __restrict__ o1, bf16_t* __restrict__ o2)
{
    const float* in  = (blockIdx.z == 0) ? i0 : (blockIdx.z == 1) ? i1 : i2;
    bf16_t*      out = (blockIdx.z == 0) ? o0 : (blockIdx.z == 1) ? o1 : o2;
    const long i = ((long)blockIdx.x * 256 + threadIdx.x) * 8;
    f32x4 a = *(const f32x4*)(in + i);
    f32x4 b = *(const f32x4*)(in + i + 4);
    bf16x8 o;
    #pragma unroll
    for (int j = 0; j < 4; ++j) { o[j] = (bf16_t)a[j]; o[4 + j] = (bf16_t)b[j]; }
    *(bf16x8*)(out + i) = o;
}

// ---------------------------------------------------------------------------
// GEMM v4: C[M,N] = A[M,K](bf16) @ B[N,K](bf16)^T + bias(fp32).
// BM=128, BN in {64,128}, BK=32, 256 thr, 4 waves 2x2.
// Counted-vmcnt 2-deep pipeline (T4): prologue stages tiles 0,1; per iter:
//   s_waitcnt vmcnt(NLD)   <- own tile-t loads landed (t+1's NLD in flight)
//   s_barrier              <- all waves landed tile t
//   ds_read + MFMA on buf
//   s_barrier              <- all waves done reading buf
//   STAGE(t+2, buf)        <- loads stay in flight across both barriers
// Never drains vmcnt to 0 in the main loop (the round-4 __syncthreads did,
// serializing a full load round-trip per K-step -> MfmaUtil stuck at 14%).
// sched_barrier(0) fences pin ds_reads between the barriers (rule #18).
// 4-chunk XOR swizzle (source-pre-swizzled, linear LDS dest) as round 4.
// ---------------------------------------------------------------------------
template<bool GELU, bool RES, bool OUTBF, int BN>
__device__ __forceinline__
void gemm4_body(const bf16_t* __restrict__ A, const bf16_t* __restrict__ B,
                const float* __restrict__ bias, const float* __restrict__ Res,
                void* __restrict__ Cout, int M, int N, int K)
{
    constexpr int NI  = BN / 32;          // n-subtiles per wave
    constexpr int BBY = BN * 64;          // B tile bytes per buffer
    __shared__ __align__(16) bf16_t As[2][128 * 32];   // 2 x 8 KB
    __shared__ __align__(16) char   Bs[2][BBY];        // 2 x (4|8) KB

    const int t = threadIdx.x;
    const int w = t >> 6, l = t & 63;
    const int wm = (w >> 1) * 64, wn = (w & 1) * (BN / 2);
    const int g = l >> 4, fr = l & 15, e2 = fr & 3;

    // staging: row = t>>2 (+64 for round 2), 16B chunk t&3; source column
    // pre-swizzled: chunk (t&3) ^ (row&3)  (row&3 == (t>>2)&3, both rounds)
    const int  sCol = (((t & 3) ^ ((t >> 2) & 3)) << 3);  // bf16 elems
    const long aRow = (long)blockIdx.x * 128 + (t >> 2);
    const long bRow = (long)blockIdx.y * BN  + (t >> 2);

    char* aW = (char*)As + w * 1024;
    char* bW = (char*)Bs + w * 1024;

    f32x4 acc[4][NI] = {};
    const int nIter = K / 32;

    auto STAGE = [&](int k0, int buf) {
        load_lds16(A + aRow * K + (k0 + sCol),        aW + buf * 8192);
        load_lds16(A + (aRow + 64) * K + (k0 + sCol), aW + buf * 8192 + 4096);
        if (BN == 128) {
            load_lds16(B + bRow * K + (k0 + sCol),        bW + buf * BBY);
            load_lds16(B + (bRow + 64) * K + (k0 + sCol), bW + buf * BBY + 4096);
        } else {
            load_lds16(B + bRow * K + (k0 + sCol), bW + buf * BBY);
        }
    };

    STAGE(0, 0);
    STAGE(32, 1);
    int buf = 0;
    for (int it = 0; it < nIter; ++it) {
        // wait: own tile-it loads landed; keep tile-(it+1)'s NLD in flight
        if (it + 1 < nIter) {
            if (BN == 128) asm volatile("s_waitcnt vmcnt(4)" ::: "memory");
            else           asm volatile("s_waitcnt vmcnt(3)" ::: "memory");
        } else {
            asm volatile("s_waitcnt vmcnt(0)" ::: "memory");
        }
        __builtin_amdgcn_sched_barrier(0);
        __builtin_amdgcn_s_barrier();          // all waves landed tile it
        __builtin_amdgcn_sched_barrier(0);

        const char* ab = (const char*)As + buf * 8192;
        const char* bb = (const char*)Bs + buf * BBY;
        bf16x8 af[4], bfr[NI];
        #pragma unroll
        for (int mi = 0; mi < 4; ++mi)
            af[mi] = *(const bf16x8*)(ab + (wm + mi * 16 + fr) * 64 + ((g ^ e2) << 4));
        #pragma unroll
        for (int ni = 0; ni < NI; ++ni)
            bfr[ni] = *(const bf16x8*)(bb + (wn + ni * 16 + fr) * 64 + ((g ^ e2) << 4));
        #pragma unroll
        for (int mi = 0; mi < 4; ++mi)
            #pragma unroll
            for (int ni = 0; ni < NI; ++ni)
                acc[mi][ni] = __builtin_amdgcn_mfma_f32_16x16x32_bf16(
                    af[mi], bfr[ni], acc[mi][ni], 0, 0, 0);

        __builtin_amdgcn_sched_barrier(0);     // pin ds_reads above barrier
        __builtin_amdgcn_s_barrier();          // all waves done reading buf
        if (it + 2 < nIter) STAGE((it + 2) * 32, buf);
        buf ^= 1;
    }

    // epilogue: C/D layout col = l&15, row = (l>>4)*4 + reg
    bf16_t* Cb = (bf16_t*)Cout;
    float*  Cf = (float*)Cout;
    const int r0 = g * 4;
    #pragma unroll
    for (int ni = 0; ni < NI; ++ni) {
        const int gc = blockIdx.y * BN + wn + ni * 16 + fr;
        const float bv = bias[gc];
        #pragma unroll
        for (int mi = 0; mi < 4; ++mi) {
            #pragma unroll
            for (int r = 0; r < 4; ++r) {
                const long gr = (long)blockIdx.x * 128 + wm + mi * 16 + r0 + r;
                float vv = acc[mi][ni][r] + bv;
                if (GELU) vv = gelu_f(vv);
                if (RES)  vv += Res[gr * N + gc];
                if (OUTBF) Cb[gr * N + gc] = (bf16_t)vv;
                else       Cf[gr * N + gc] = vv;
            }
        }
    }
}

template<bool GELU, bool RES, bool OUTBF, int BN>
__global__ __launch_bounds__(256, 2)
void gemm4_kernel(const bf16_t* __restrict__ A, const bf16_t* __restrict__ B,
                  const float* __restrict__ bias, const float* Res,
                  void* Cout, int M, int N, int K)
{
    gemm4_body<GELU, RES, OUTBF, BN>(A, B, bias, Res, Cout, M, N, K);
}

// Fused Q/K/V projection (bf16 weights): grid.z selects weight/bias/output.
__global__ __launch_bounds__(256, 2)
void qkv4_kernel(const bf16_t* __restrict__ A,
                 const bf16_t* __restrict__ B0, const bf16_t* __restrict__ B1,
                 const bf16_t* __restrict__ B2,
                 const float* __restrict__ b0, const float* __restrict__ b1,
                 const float* __restrict__ b2,
                 bf16_t* C0, bf16_t* C1, bf16_t* C2, int M, int N, int K)
{
    const int z = blockIdx.z;
    const bf16_t* B    = (z == 0) ? B0 : (z == 1) ? B1 : B2;
    const float*  bias = (z == 0) ? b0 : (z == 1) ? b1 : b2;
    bf16_t*       C    = (z == 0) ? C0 : (z == 1) ? C1 : C2;
    gemm4_body<false, false, true, 64>(A, B, bias, nullptr, C, M, N, K);
}

// ---------------------------------------------------------------------------
// LayerNorm over D=1024: fp32 in -> bf16 out. One 256-thr block per token.
// ---------------------------------------------------------------------------
__global__ __launch_bounds__(256)
void ln_kernel(const float* __restrict__ in, const float* __restrict__ w,
               const float* __restrict__ b, bf16_t* __restrict__ out)
{
    const long row = blockIdx.x;
    const int t = threadIdx.x;
    f32x4 xv = *(const f32x4*)(in + row * DMODEL + t * 4);
    float s  = xv[0] + xv[1] + xv[2] + xv[3];
    float ss = xv[0]*xv[0] + xv[1]*xv[1] + xv[2]*xv[2] + xv[3]*xv[3];
    #pragma unroll
    for (int off = 32; off; off >>= 1) {
        s  += __shfl_xor(s, off);
        ss += __shfl_xor(ss, off);
    }
    __shared__ float sbuf[4], ssbuf[4];
    if ((t & 63) == 0) { sbuf[t >> 6] = s; ssbuf[t >> 6] = ss; }
    __syncthreads();
    s  = sbuf[0] + sbuf[1] + sbuf[2] + sbuf[3];
    ss = ssbuf[0] + ssbuf[1] + ssbuf[2] + ssbuf[3];
    const float mean = s * (1.f / DMODEL);
    const float var  = ss * (1.f / DMODEL) - mean * mean;
    const float rstd = rsqrtf(var + 1e-5f);
    f32x4 wv = *(const f32x4*)(w + t * 4);
    f32x4 bv = *(const f32x4*)(b + t * 4);
    bf16x4 o4;
    #pragma unroll
    for (int j = 0; j < 4; ++j)
        o4[j] = (bf16_t)((xv[j] - mean) * rstd * wv[j] + bv[j]);
    *(bf16x4*)(out + row * DMODEL + t * 4) = o4;
}

// ---------------------------------------------------------------------------
// Flash attention (non-causal, mask==0): block = (b,h, 64 q rows), 4 waves,
// wave w owns q rows [16w,16w+16). bf16 MFMA 16x16x32, fp32 online softmax.
// K/V tiles (64s x 64d) staged per step; V stored transposed [d][s].
// Q/K/V LDS rows XOR-swizzled in 16B chunks (p = c ^ (row&7)) -> 2-way banks.
// P round-trips through per-wave LDS (C-layout -> A-layout), m120 pattern.
// Grid MUST be B*H*(T/64) = 1024 blocks.
// ---------------------------------------------------------------------------
__global__ __launch_bounds__(256)
void attn_kernel(const bf16_t* __restrict__ q, const bf16_t* __restrict__ k,
                 const bf16_t* __restrict__ v, bf16_t* __restrict__ o)
{
    __shared__ bf16_t Qs[64 * 64], Ks[64 * 64], Vs[64 * 64];
    __shared__ bf16_t Ps[4][16 * 64];
    const int t = threadIdx.x, w = t >> 6, l = t & 63;
    const int g = l >> 4, fr = l & 15, e = fr & 7;
    const int qblk = blockIdx.x & 15, bh = blockIdx.x >> 4;   // bh in 0..63
    const int b = bh >> 4, h = bh & 15;
    const long base = (long)b * TSEQ * DMODEL + h * HDIM;

    // staging map: row = t>>2 (64 rows), 16B-chunk pair c2, c2+1
    const int sr = t >> 2, c2 = (t & 3) * 2;
    const int p0 = c2 ^ (sr & 7), p1 = (c2 + 1) ^ (sr & 7);
    const int s7 = sr & 7, scs = sr >> 3;

    {   // stage Q once
        const bf16_t* qg = q + base + (long)(qblk * 64 + sr) * DMODEL + c2 * 8;
        bf16x8 a0 = *(const bf16x8*)qg, a1 = *(const bf16x8*)(qg + 8);
        *(bf16x8*)((char*)Qs + sr * 128 + p0 * 16) = a0;
        *(bf16x8*)((char*)Qs + sr * 128 + p1 * 16) = a1;
    }
    __syncthreads();
    bf16x8 qf[2];
    {
        const char* qp = (const char*)Qs + (16 * w + fr) * 128;
        qf[0] = *(const bf16x8*)(qp + ((g       ^ e) << 4));
        qf[1] = *(const bf16x8*)(qp + (((g + 4) ^ e) << 4));
    }

    float m_[4], lsum[4] = {0.f, 0.f, 0.f, 0.f};
    #pragma unroll
    for (int r = 0; r < 4; ++r) m_[r] = -1e30f;
    f32x4 oacc[4] = {};

    for (int s0 = 0; s0 < TSEQ; s0 += 64) {
        __syncthreads();
        {   // stage K tile
            const bf16_t* kg = k + base + (long)(s0 + sr) * DMODEL + c2 * 8;
            bf16x8 a0 = *(const bf16x8*)kg, a1 = *(const bf16x8*)(kg + 8);
            *(bf16x8*)((char*)Ks + sr * 128 + p0 * 16) = a0;
            *(bf16x8*)((char*)Ks + sr * 128 + p1 * 16) = a1;
        }
        {   // stage V transposed: thread loads V[s=sr][d0..d0+16), scatters to Vs[d][s]
            const bf16_t* vg = v + base + (long)(s0 + sr) * DMODEL + (t & 3) * 16;
            bf16x8 v0 = *(const bf16x8*)vg, v1 = *(const bf16x8*)(vg + 8);
            #pragma unroll
            for (int u = 0; u < 8; ++u) {
                int d0 = (t & 3) * 16 + u;
                ((bf16_t*)((char*)Vs + d0 * 128 + ((scs ^ (d0 & 7)) << 4)))[s7] = v0[u];
                int d1 = d0 + 8;
                ((bf16_t*)((char*)Vs + d1 * 128 + ((scs ^ (d1 & 7)) << 4)))[s7] = v1[u];
            }
        }
        __syncthreads();

        // S = Q K^T  (4 s-subtiles x 2 k-steps)
        f32x4 sacc[4] = {};
        #pragma unroll
        for (int ni = 0; ni < 4; ++ni) {
            const char* kp = (const char*)Ks + (ni * 16 + fr) * 128;
            bf16x8 kf0 = *(const bf16x8*)(kp + ((g       ^ e) << 4));
            bf16x8 kf1 = *(const bf16x8*)(kp + (((g + 4) ^ e) << 4));
            sacc[ni] = __builtin_amdgcn_mfma_f32_16x16x32_bf16(qf[0], kf0, sacc[ni], 0, 0, 0);
            sacc[ni] = __builtin_amdgcn_mfma_f32_16x16x32_bf16(qf[1], kf1, sacc[ni], 0, 0, 0);
        }

        // online softmax; S row = g*4 + r (local q), col = ni*16 + fr (local s)
        #pragma unroll
        for (int r = 0; r < 4; ++r) {
            float a = fmaxf(fmaxf(sacc[0][r], sacc[1][r]),
                            fmaxf(sacc[2][r], sacc[3][r])) * 0.125f;
            #pragma unroll
            for (int off = 1; off < 16; off <<= 1) a = fmaxf(a, __shfl_xor(a, off));
            float mnew  = fmaxf(m_[r], a);
            float alpha = __expf(m_[r] - mnew);
            m_[r] = mnew;
            float sum = 0.f;
            #pragma unroll
            for (int ni = 0; ni < 4; ++ni) {
                float p = __expf(sacc[ni][r] * 0.125f - mnew);
                sum += p;
                Ps[w][(g * 4 + r) * 64 + ni * 16 + fr] = (bf16_t)p;
            }
            #pragma unroll
            for (int off = 1; off < 16; off <<= 1) sum += __shfl_xor(sum, off);
            lsum[r] = lsum[r] * alpha + sum;
            #pragma unroll
            for (int di = 0; di < 4; ++di) oacc[di][r] *= alpha;
        }

        // O += P V   (P: A-layout from per-wave LDS; V^T rows, swizzled)
        bf16x8 pf0 = *(const bf16x8*)&Ps[w][fr * 64 + g * 8];
        bf16x8 pf1 = *(const bf16x8*)&Ps[w][fr * 64 + 32 + g * 8];
        #pragma unroll
        for (int di = 0; di < 4; ++di) {
            const char* vp = (const char*)Vs + (di * 16 + fr) * 128;
            bf16x8 vf0 = *(const bf16x8*)(vp + ((g       ^ e) << 4));
            bf16x8 vf1 = *(const bf16x8*)(vp + (((g + 4) ^ e) << 4));
            oacc[di] = __builtin_amdgcn_mfma_f32_16x16x32_bf16(pf0, vf0, oacc[di], 0, 0, 0);
            oacc[di] = __builtin_amdgcn_mfma_f32_16x16x32_bf16(pf1, vf1, oacc[di], 0, 0, 0);
        }
    }

    #pragma unroll
    for (int r = 0; r < 4; ++r) {
        const float inv = 1.f / lsum[r];
        const long tq = qblk * 64 + 16 * w + g * 4 + r;
        #pragma unroll
        for (int di = 0; di < 4; ++di)
            o[base + tq * DMODEL + di * 16 + fr] = (bf16_t)(oacc[di][r] * inv);
    }
}

// ---------------------------------------------------------------------------
extern "C" void kernel_launch(void* const* d_in, const int* in_sizes, int n_in,
                              void* d_out, int out_size, void* d_ws, size_t ws_size,
                              hipStream_t stream)
{
    const float* hs    = (const float*)d_in[0];
    const float* ln1w  = (const float*)d_in[2];
    const float* ln1b  = (const float*)d_in[3];
    const float* qw    = (const float*)d_in[4];
    const float* qbias = (const float*)d_in[5];
    const float* kw    = (const float*)d_in[6];
    const float* kbias = (const float*)d_in[7];
    const float* vw    = (const float*)d_in[8];
    const float* vbias = (const float*)d_in[9];
    const float* ow    = (const float*)d_in[10];
    const float* obias = (const float*)d_in[11];
    const float* ln2w  = (const float*)d_in[12];
    const float* ln2b  = (const float*)d_in[13];
    const float* fc1w  = (const float*)d_in[14];
    const float* fc1b  = (const float*)d_in[15];
    const float* fc2w  = (const float*)d_in[16];
    const float* fc2b  = (const float*)d_in[17];
    const float* lnpw  = (const float*)d_in[18];
    const float* lnpb  = (const float*)d_in[19];
    const float* p1w   = (const float*)d_in[20];
    const float* p1b   = (const float*)d_in[21];
    const float* p2w   = (const float*)d_in[22];
    const float* p2b   = (const float*)d_in[23];

    // ws (56 MB): h fp32 [0,16) | x bf16 [16,24) | q [24,32) | k [32,40)
    //             | v [40,48) | tail [48,56)
    // Dead-window reuse for bf16 weights:
    //   qkv weights -> tail   (free between fc2(i-1) and fc1(i))
    //   ow          -> qbuf   (free after attn(i), until fc1(i))
    //   fc1w        -> d_out  (32 MB fp32 output, only written by final GEMM)
    //   fc2w        -> x      (free after fc1(i) consumed x)
    //   p1w -> kbuf, p2w -> vbuf (free after final fc2)
    float*  h    = (float*)d_ws;
    bf16_t* x    = (bf16_t*)(h + (long)NTOK * DMODEL);
    bf16_t* qbuf = x    + (long)NTOK * DMODEL;
    bf16_t* kbuf = qbuf + (long)NTOK * DMODEL;
    bf16_t* vbuf = kbuf + (long)NTOK * DMODEL;
    bf16_t* tail = vbuf + (long)NTOK * DMODEL;
    bf16_t* obuf = x;      // x dead after V-proj; attention writes o here
    bf16_t* fbuf = qbuf;   // fc1 out: 32 MB spans q,k,v,tail

    bf16_t* qw16   = tail;                       // 3 x 1M elems (6 MB)
    bf16_t* kw16   = tail + (long)DMODEL * DMODEL;
    bf16_t* vw16   = kw16 + (long)DMODEL * DMODEL;
    bf16_t* ow16   = qbuf;                       // 2 MB in dead qbuf
    bf16_t* fc1w16 = (bf16_t*)d_out;             // 8 MB in dead d_out (32 MB)
    bf16_t* fc2w16 = x;                          // 8 MB exact fit in dead x
    bf16_t* p1w16  = kbuf;                       // 2 MB
    bf16_t* p2w16  = vbuf;                       // 4 MB

    hipMemcpyAsync(h, hs, (size_t)NTOK * DMODEL * sizeof(float),
                   hipMemcpyDeviceToDevice, stream);

    const dim3 blk(256);
    const dim3 gD(NTOK / 128, DMODEL / 64);          // N=1024, BN=64: 512 blocks
    const dim3 gQKV(NTOK / 128, DMODEL / 64, 3);     // 1536 blocks
    const dim3 gF1(NTOK / 128, FDIM / 128);          // N=4096, BN=128: 1024 blocks
    const dim3 gOut(NTOK / 128, OUTDIM / 128);       // N=2048, BN=128: 512 blocks
    const int  gAttn = (NTOK / 64) * NHEAD;          // 1024 blocks
    const int  cvtD  = (DMODEL * DMODEL) / 2048;     // 512 blocks per 1M elems

    for (int i = 0; i < NLAYER; ++i) {
        const long wD = (long)i * DMODEL * DMODEL;
        const long wF = (long)i * FDIM * DMODEL;
        // qkv weights -> bf16 in tail; fc1w -> bf16 in d_out
        cvt3_kernel<<<dim3(cvtD, 1, 3), blk, 0, stream>>>(
            qw + wD, kw + wD, vw + wD, qw16, kw16, vw16);
        cvt_kernel<<<cvtD * 4, blk, 0, stream>>>(fc1w + wF, fc1w16);
        ln_kernel<<<NTOK, blk, 0, stream>>>(h, ln1w + i * DMODEL, ln1b + i * DMODEL, x);
        qkv4_kernel<<<gQKV, blk, 0, stream>>>(x, qw16, kw16, vw16,
                                              qbias + i * DMODEL, kbias + i * DMODEL, vbias + i * DMODEL,
                                              qbuf, kbuf, vbuf, NTOK, DMODEL, DMODEL);
        attn_kernel<<<gAttn, blk, 0, stream>>>(qbuf, kbuf, vbuf, obuf);
        // ow -> bf16 in dead qbuf; h += obuf @ ow^T + ob (plain RMW)
        cvt_kernel<<<cvtD, blk, 0, stream>>>(ow + wD, ow16);
        gemm4_kernel<false, true, false, 64><<<gD, blk, 0, stream>>>(
            obuf, ow16, obias + i * DMODEL, h, h, NTOK, DMODEL, DMODEL);
        ln_kernel<<<NTOK, blk, 0, stream>>>(h, ln2w + i * DMODEL, ln2b + i * DMODEL, x);
        gemm4_kernel<true, false, true, 128><<<gF1, blk, 0, stream>>>(
            x, fc1w16, fc1b + (long)i * FDIM, nullptr, fbuf, NTOK, FDIM, DMODEL);
        // fc2w -> bf16 in x (x consumed by fc1); h += fbuf @ fc2w^T + fc2b
        cvt_kernel<<<cvtD * 4, blk, 0, stream>>>(fc2w + wF, fc2w16);
        gemm4_kernel<false, true, false, 64><<<gD, blk, 0, stream>>>(
            fbuf, fc2w16, fc2b + i * DMODEL, h, h, NTOK, DMODEL, FDIM);
    }

    ln_kernel<<<NTOK, blk, 0, stream>>>(h, lnpw, lnpb, x);
    cvt_kernel<<<cvtD, blk, 0, stream>>>(p1w, p1w16);
    gemm4_kernel<true, false, true, 64><<<gD, blk, 0, stream>>>(
        x, p1w16, p1b, nullptr, qbuf, NTOK, DMODEL, DMODEL);
    cvt_kernel<<<cvtD * 2, blk, 0, stream>>>(p2w, p2w16);
    gemm4_kernel<false, false, false, 128><<<gOut, blk, 0, stream>>>(
        qbuf, p2w16, p2b, nullptr, d_out, NTOK, OUTDIM, DMODEL);
}